// Round 7
// baseline (75.168 us; speedup 1.0000x reference)
//
#include <hip/hip_runtime.h>

#define VOCAB 100000
#define D     300
#define B     256
#define L     1000
#define H     512
#define C     5

#define SPLIT 10
#define CHUNK (L / SPLIT)   // 100 rows per gather block
#define D4f   (D / 4)       // 75 float4 per row

// ws layout (floats)
#define WS_PARTIAL 0
#define WS_H1      (B * SPLIT * D)       // 768000
#define WS_H2      (WS_H1 + B * H)       // +131072 -> 4.12 MB total

// ---------------------------------------------------------------------------
// K1: gather + partial sum — R1's proven kernel, verbatim (~15.7 us).
// grid (B, SPLIT) = 2560 blocks x 320 thr: high occupancy gives wave-level
// memory parallelism without fighting the register allocator.
// ---------------------------------------------------------------------------
__global__ __launch_bounds__(320) void gather_sum_kernel(
    const float* __restrict__ emb, const int* __restrict__ docs,
    float* __restrict__ partial) {
  const int b = blockIdx.x;
  const int s = blockIdx.y;
  const int t = threadIdx.x;
  const int rg = t / 80;
  const int lane = t - rg * 80;

  __shared__ int sidx[CHUNK];
  if (t < CHUNK) sidx[t] = docs[b * L + s * CHUNK + t];
  __syncthreads();

  float ax = 0.f, ay = 0.f, az = 0.f, aw = 0.f;
  if (lane < D4f) {
#pragma unroll 5
    for (int l = 0; l < CHUNK; l += 4) {
      const int idx = sidx[l + rg];
      const float4 v =
          reinterpret_cast<const float4*>(emb + (size_t)idx * D)[lane];
      ax += v.x; ay += v.y; az += v.z; aw += v.w;
    }
  }

  __shared__ float4 sred[3][D4f];
  if (rg > 0 && lane < D4f) sred[rg - 1][lane] = make_float4(ax, ay, az, aw);
  __syncthreads();
  if (rg == 0 && lane < D4f) {
#pragma unroll
    for (int g = 0; g < 3; ++g) {
      const float4 v = sred[g][lane];
      ax += v.x; ay += v.y; az += v.z; aw += v.w;
    }
    reinterpret_cast<float4*>(partial + (size_t)(b * SPLIT + s) * D)[lane] =
        make_float4(ax, ay, az, aw);
  }
}

// ---------------------------------------------------------------------------
// K2: h1 = relu(avg @ W1 + b1), with partial-reduce folded in.
// grid (16 doc-tiles, 16 col-tiles) = 256 blocks x 1024 thr.
// W1 slab [300][32] staged to LDS (<=3 independent loads/thread); compute
// reads weights from LDS -> per-thread global serial chain is ~13 loads max.
// Thread = (doc 16, cg 8 [4 cols], ks 8 [K-slice]); LDS combine.
// ---------------------------------------------------------------------------
__global__ __launch_bounds__(1024) void l1_kernel(
    const float* __restrict__ partial, const int* __restrict__ dlen,
    const float* __restrict__ W1, const float* __restrict__ b1,
    float* __restrict__ h1) {
  const int dq = blockIdx.x;
  const int cq = blockIdx.y;
  const int t = threadIdx.x;

  __shared__ float4 s_avg[16][D4f];          // 19200 B
  __shared__ float  s_w[D][32];              // 38400 B
  __shared__ float  s_comb[8][16][32];       // 16384 B

  // Stage W1 slab: 300 rows x 8 float4 = 2400 loads, <=3 per thread.
  for (int o = t; o < D * 8; o += 1024) {
    const int k = o >> 3, c4 = o & 7;
    *reinterpret_cast<float4*>(&s_w[k][c4 * 4]) =
        *reinterpret_cast<const float4*>(W1 + (size_t)k * H + cq * 32 + c4 * 4);
  }
  // Reduce partial -> avg: 1200 float4 outputs, 10 independent loads each.
  for (int o = t; o < 16 * D4f; o += 1024) {
    const int doc = o / D4f, c4 = o - doc * D4f;
    const int b = dq * 16 + doc;
    const float4* p =
        reinterpret_cast<const float4*>(partial) + (size_t)b * (SPLIT * D4f) + c4;
    float4 v[SPLIT];
#pragma unroll
    for (int s = 0; s < SPLIT; ++s) v[s] = p[s * D4f];
    float ax = 0.f, ay = 0.f, az = 0.f, aw = 0.f;
#pragma unroll
    for (int s = 0; s < SPLIT; ++s) {
      ax += v[s].x; ay += v[s].y; az += v[s].z; aw += v[s].w;
    }
    const float inv = 1.f / (float)dlen[b];
    s_avg[doc][c4] = make_float4(ax * inv, ay * inv, az * inv, aw * inv);
  }
  __syncthreads();

  // Compute from LDS.
  {
    const int doc = t & 15;
    const int cg = (t >> 4) & 7;
    const int ks = t >> 7;                      // 8 K-slices of 10/9 float4
    const int nf4 = (ks < 3) ? 10 : 9;
    const int o4 = (ks < 3) ? 10 * ks : 30 + 9 * (ks - 3);
    float ax = 0.f, ay = 0.f, az = 0.f, aw = 0.f;
    for (int j = 0; j < nf4; ++j) {
      const float4 x4 = s_avg[doc][o4 + j];
      const int k = 4 * (o4 + j);
      const float4 w0 = *reinterpret_cast<const float4*>(&s_w[k + 0][cg * 4]);
      const float4 w1 = *reinterpret_cast<const float4*>(&s_w[k + 1][cg * 4]);
      const float4 w2 = *reinterpret_cast<const float4*>(&s_w[k + 2][cg * 4]);
      const float4 w3 = *reinterpret_cast<const float4*>(&s_w[k + 3][cg * 4]);
      ax += x4.x * w0.x + x4.y * w1.x + x4.z * w2.x + x4.w * w3.x;
      ay += x4.x * w0.y + x4.y * w1.y + x4.z * w2.y + x4.w * w3.y;
      az += x4.x * w0.z + x4.y * w1.z + x4.z * w2.z + x4.w * w3.z;
      aw += x4.x * w0.w + x4.y * w1.w + x4.z * w2.w + x4.w * w3.w;
    }
    *reinterpret_cast<float4*>(&s_comb[ks][doc][cg * 4]) =
        make_float4(ax, ay, az, aw);
  }
  __syncthreads();

  if (t < 512) {
    const int dd = t >> 5, col = t & 31;
    float v = b1[cq * 32 + col];
#pragma unroll
    for (int s = 0; s < 8; ++s) v += s_comb[s][dd][col];
    h1[(size_t)(dq * 16 + dd) * H + cq * 32 + col] = fmaxf(v, 0.f);
  }
}

// ---------------------------------------------------------------------------
// K3: h2 = relu(h1 @ W2 + b2). Same structure, K = 512 (8 slices x 16 f4).
// LDS: x 32 KB + W2 slab 64 KB + comb 16 KB = 112 KB.
// ---------------------------------------------------------------------------
__global__ __launch_bounds__(1024) void l2_kernel(
    const float* __restrict__ h1, const float* __restrict__ W2,
    const float* __restrict__ b2, float* __restrict__ h2) {
  const int dq = blockIdx.x;
  const int cq = blockIdx.y;
  const int t = threadIdx.x;

  __shared__ float4 s_x[16][H / 4];          // 32768 B
  __shared__ float  s_w[H][32];              // 65536 B
  __shared__ float  s_comb[8][16][32];       // 16384 B

  // Stage W2 slab: 4096 float4, 4 per thread.
  for (int o = t; o < H * 8; o += 1024) {
    const int k = o >> 3, c4 = o & 7;
    *reinterpret_cast<float4*>(&s_w[k][c4 * 4]) =
        *reinterpret_cast<const float4*>(W2 + (size_t)k * H + cq * 32 + c4 * 4);
  }
  // Stage x: 2048 float4, 2 per thread.
  for (int o = t; o < 16 * (H / 4); o += 1024) {
    const int doc = o >> 7, c4 = o & 127;
    s_x[doc][c4] =
        reinterpret_cast<const float4*>(h1 + (size_t)(dq * 16 + doc) * H)[c4];
  }
  __syncthreads();

  {
    const int doc = t & 15;
    const int cg = (t >> 4) & 7;
    const int ks = t >> 7;
    float ax = 0.f, ay = 0.f, az = 0.f, aw = 0.f;
    for (int j = 0; j < 16; ++j) {
      const int kk = ks * 16 + j;
      const float4 x4 = s_x[doc][kk];
      const int k = 4 * kk;
      const float4 w0 = *reinterpret_cast<const float4*>(&s_w[k + 0][cg * 4]);
      const float4 w1 = *reinterpret_cast<const float4*>(&s_w[k + 1][cg * 4]);
      const float4 w2 = *reinterpret_cast<const float4*>(&s_w[k + 2][cg * 4]);
      const float4 w3 = *reinterpret_cast<const float4*>(&s_w[k + 3][cg * 4]);
      ax += x4.x * w0.x + x4.y * w1.x + x4.z * w2.x + x4.w * w3.x;
      ay += x4.x * w0.y + x4.y * w1.y + x4.z * w2.y + x4.w * w3.y;
      az += x4.x * w0.z + x4.y * w1.z + x4.z * w2.z + x4.w * w3.z;
      aw += x4.x * w0.w + x4.y * w1.w + x4.z * w2.w + x4.w * w3.w;
    }
    *reinterpret_cast<float4*>(&s_comb[ks][doc][cg * 4]) =
        make_float4(ax, ay, az, aw);
  }
  __syncthreads();

  if (t < 512) {
    const int dd = t >> 5, col = t & 31;
    float v = b2[cq * 32 + col];
#pragma unroll
    for (int s = 0; s < 8; ++s) v += s_comb[s][dd][col];
    h2[(size_t)(dq * 16 + dd) * H + cq * 32 + col] = fmaxf(v, 0.f);
  }
}

// ---------------------------------------------------------------------------
// K4: out = h2 @ W3 + b3. 256 blocks x 64 threads; W3 is 10 KB (L1/L2-hot).
// ---------------------------------------------------------------------------
__global__ __launch_bounds__(64) void head_kernel(
    const float* __restrict__ h2, const float* __restrict__ W3,
    const float* __restrict__ b3, float* __restrict__ out) {
  const int b = blockIdx.x;
  const int l = threadIdx.x;
  float acc[C] = {0.f, 0.f, 0.f, 0.f, 0.f};
#pragma unroll
  for (int i = 0; i < H / 64; ++i) {
    const int h = i * 64 + l;
    const float v = h2[(size_t)b * H + h];
#pragma unroll
    for (int c = 0; c < C; ++c) acc[c] += v * W3[h * C + c];
  }
#pragma unroll
  for (int c = 0; c < C; ++c) {
    float a = acc[c];
#pragma unroll
    for (int off = 32; off > 0; off >>= 1) a += __shfl_down(a, off);
    if (l == 0) out[b * C + c] = a + b3[c];
  }
}

// ---------------------------------------------------------------------------
extern "C" void kernel_launch(void* const* d_in, const int* in_sizes, int n_in,
                              void* d_out, int out_size, void* d_ws,
                              size_t ws_size, hipStream_t stream) {
  const float* emb  = (const float*)d_in[0];
  const float* W1   = (const float*)d_in[1];
  const float* b1   = (const float*)d_in[2];
  const float* W2   = (const float*)d_in[3];
  const float* b2   = (const float*)d_in[4];
  const float* W3   = (const float*)d_in[5];
  const float* b3   = (const float*)d_in[6];
  const int*   docs = (const int*)d_in[7];
  const int*   dlen = (const int*)d_in[8];
  float* out = (float*)d_out;

  float* ws = (float*)d_ws;
  float* partial = ws + WS_PARTIAL;
  float* h1 = ws + WS_H1;
  float* h2 = ws + WS_H2;

  dim3 g1(B, SPLIT);
  gather_sum_kernel<<<g1, 320, 0, stream>>>(emb, docs, partial);
  dim3 gl(16, 16);
  l1_kernel<<<gl, 1024, 0, stream>>>(partial, dlen, W1, b1, h1);
  l2_kernel<<<gl, 1024, 0, stream>>>(h1, W2, b2, h2);
  head_kernel<<<B, 64, 0, stream>>>(h2, W3, b3, out);
}